// Round 4
// baseline (274.190 us; speedup 1.0000x reference)
//
#include <hip/hip_runtime.h>
#include <stdint.h>

typedef unsigned short u16;
typedef unsigned int   u32;
typedef __attribute__((ext_vector_type(8))) short bf16x8;  // 8 bf16 = 4 VGPR
typedef __attribute__((ext_vector_type(4))) short bf16x4;  // 4 bf16 = 2 VGPR
typedef __attribute__((ext_vector_type(4))) float f32x4;   // MFMA C/D frag

#define NT ((size_t)8388608)   // 32*1024*256 elements

// ---------- helpers ----------
__device__ __forceinline__ float bf2f(u16 u) {
  union { float f; u32 i; } v; v.i = ((u32)u) << 16; return v.f;
}
__device__ __forceinline__ u16 f2bf(float f) {
  union { float f; u32 i; } v; v.f = f;
  u32 r = (v.i + 0x7fffu + ((v.i >> 16) & 1u)) >> 16;   // RNE
  return (u16)r;
}
__device__ __forceinline__ u32 fbits(float f) {
  union { float f; u32 i; } v; v.f = f; return v.i;
}
// bf16-vs-f32 buffer sniff (64-lane ballot on exponent-byte position)
__device__ __forceinline__ int detect_bf16(const u32* __restrict__ xd) {
  u32 w = xd[threadIdx.x & 63];
  u32 e = (w >> 8) & 0x7fu;
  unsigned long long m = __ballot((e >= 0x38u) && (e <= 0x41u));
  return __popcll(m) > 32;
}
// async 16B/lane global->LDS (dest = wave-uniform base + lane*16)
__device__ __forceinline__ void gld16(const void* g, void* l) {
  __builtin_amdgcn_global_load_lds((const __attribute__((address_space(1))) u32*)g,
                                   (__attribute__((address_space(3))) u32*)l, 16, 0, 0);
}

// ---------- prologue: x transpose (0..2047) + Wq/Wk/Wv prep (2048..2239) + optional Wo (2240..2303) ----------
__global__ void __launch_bounds__(256) prologue_kernel(const void* __restrict__ xin,
                                                       u16* __restrict__ xT,
                                                       const void* __restrict__ W0, const void* __restrict__ W1,
                                                       const void* __restrict__ W2, const void* __restrict__ b0,
                                                       const void* __restrict__ b1, const void* __restrict__ b2,
                                                       u16* __restrict__ wdst, float* __restrict__ bdst,
                                                       const void* __restrict__ Wo, const void* __restrict__ bo,
                                                       const void* __restrict__ gm, u16* __restrict__ wodst,
                                                       float* __restrict__ bodst) {
  const int blk = blockIdx.x;
  const int tid = threadIdx.x;
  const int isbf = detect_bf16((const u32*)xin);
  if (blk < 2048) {
    const int s0 = (blk & 15) * 64, c0 = ((blk >> 4) & 3) * 64, b = blk >> 6;
    __shared__ u16 T[64][72];  // [c-local][s-local], +8 pad
    if (isbf) {
      const u16* xp = (const u16*)xin;
      for (int t = tid; t < 512; t += 256) {
        int r = t >> 3, off = (t & 7) * 8;
        *(uint4*)&T[r][off] = *(const uint4*)(xp + ((size_t)(b * 256 + c0 + r)) * 1024 + s0 + off);
      }
    } else {
      const float* xp = (const float*)xin;
      for (int t = tid; t < 512; t += 256) {
        int r = t >> 3, off = (t & 7) * 8;
        const float* s = xp + ((size_t)(b * 256 + c0 + r)) * 1024 + s0 + off;
#pragma unroll
        for (int u = 0; u < 8; u++) T[r][off + u] = f2bf(s[u]);
      }
    }
    __syncthreads();
    for (int t = tid; t < 512; t += 256) {
      int r = t >> 3, off = (t & 7) * 8;   // r = s-local, off = c-local
      union { u16 h[8]; uint4 v; } pk;
#pragma unroll
      for (int u = 0; u < 8; u++) pk.h[u] = T[off + u][r];
      *(uint4*)(xT + ((size_t)(b * 1024 + s0 + r)) * 256 + c0 + off) = pk.v;
    }
  } else if (blk < 2240) {
    const int g = blk - 2048;            // 192 blocks: 64 per weight
    const int which = g >> 6, bk = g & 63;
    const void* Ws = which == 0 ? W0 : which == 1 ? W1 : W2;
    const void* bs = which == 0 ? b0 : which == 1 ? b1 : b2;
    const int idx = bk * 1024 + tid * 4;
    u16* dst = wdst + which * 65536 + idx;
    if (isbf) {
      *(ushort4*)dst = *(const ushort4*)((const u16*)Ws + idx);
    } else {
      const float* s = (const float*)Ws + idx;
      ushort4 o; o.x = f2bf(s[0]); o.y = f2bf(s[1]); o.z = f2bf(s[2]); o.w = f2bf(s[3]);
      *(ushort4*)dst = o;
    }
    if (bk == 0) {
      bdst[which * 256 + tid] = isbf ? bf2f(((const u16*)bs)[tid]) : ((const float*)bs)[tid];
    }
  } else {
    const int g = blk - 2240;            // 64 blocks: Wo
    const int idx = g * 1024 + tid * 4;
    if (isbf) {
      *(ushort4*)(wodst + idx) = *(const ushort4*)((const u16*)Wo + idx);
    } else {
      const float* s = (const float*)Wo + idx;
      ushort4 o; o.x = f2bf(s[0]); o.y = f2bf(s[1]); o.z = f2bf(s[2]); o.w = f2bf(s[3]);
      *(ushort4*)(wodst + idx) = o;
    }
    if (g == 0) {
      bodst[tid] = isbf ? bf2f(((const u16*)bo)[tid]) : ((const float*)bo)[tid];
      if (tid == 0) bodst[256] = isbf ? bf2f(((const u16*)gm)[0]) : ((const float*)gm)[0];
    }
  }
}

// ---------- Wo prep fallback (when ws tail unavailable; runs after attn) ----------
__global__ void __launch_bounds__(256) prep_o(const void* __restrict__ Wo, const void* __restrict__ bo,
                                              const void* __restrict__ gm, u16* __restrict__ wdst,
                                              float* __restrict__ bdst, const u32* __restrict__ xdet) {
  const int isbf = detect_bf16(xdet);
  const int idx = blockIdx.x * 1024 + threadIdx.x * 4;
  if (isbf) {
    *(ushort4*)(wdst + idx) = *(const ushort4*)((const u16*)Wo + idx);
  } else {
    const float* s = (const float*)Wo + idx;
    ushort4 o; o.x = f2bf(s[0]); o.y = f2bf(s[1]); o.z = f2bf(s[2]); o.w = f2bf(s[3]);
    *(ushort4*)(wdst + idx) = o;
  }
  if (blockIdx.x == 0) {
    int t = threadIdx.x;
    bdst[t] = isbf ? bf2f(((const u16*)bo)[t]) : ((const float*)bo)[t];
    if (t == 0) bdst[256] = isbf ? bf2f(((const u16*)gm)[0]) : ((const float*)gm)[0];
  }
}

// ---------- fused QKV projection, BK=64: one launch, z = b*3 + which ----------
__global__ void __launch_bounds__(256) qkv_gemm(const u16* __restrict__ xT,
                                                const u16* __restrict__ Wall,
                                                const float* __restrict__ ball,
                                                u16* __restrict__ Qb, u16* __restrict__ Kb,
                                                u16* __restrict__ Vb) {
  const int z = blockIdx.z, b = z / 3, which = z - b * 3;
  const int tid = threadIdx.x, lane = tid & 63, wave = tid >> 6;
  const int quad = lane >> 4, l16 = lane & 15;
  const int wm = wave >> 1, wn = wave & 1;
  const u16* xb = xT + (size_t)b * 262144;
  const u16* W = Wall + which * 65536;
  int m0, n0; const u16 *Abase, *Bbase;
  if (which < 2) { m0 = blockIdx.y * 128; n0 = blockIdx.x * 128; Abase = xb; Bbase = W; }
  else           { m0 = blockIdx.x * 128; n0 = blockIdx.y * 128; Abase = W; Bbase = xb; }

  __shared__ u16 Ash[8192], Bsh[8192];   // 128 rows x 64 (128B rows)
  f32x4 acc[4][4];
#pragma unroll
  for (int i = 0; i < 4; i++)
#pragma unroll
    for (int j = 0; j < 4; j++) acc[i][j] = (f32x4){0.f, 0.f, 0.f, 0.f};

  const int srow = lane >> 3, scol = (lane & 7) * 8;
  for (int k0 = 0; k0 < 256; k0 += 64) {
    __syncthreads();   // WAR: prior frag reads done before restage lands
#pragma unroll
    for (int p = 0; p < 4; p++) {
      const int row = p * 32 + wave * 8;
      gld16(Abase + (size_t)(m0 + row + srow) * 256 + k0 + scol, &Ash[row * 64 + lane * 8]);
      gld16(Bbase + (size_t)(n0 + row + srow) * 256 + k0 + scol, &Bsh[row * 64 + lane * 8]);
    }
    __syncthreads();   // drains vmcnt before barrier
#pragma unroll
    for (int kk = 0; kk < 2; kk++) {
      bf16x8 av[4], bv[4];
#pragma unroll
      for (int i = 0; i < 4; i++) av[i] = *(const bf16x8*)&Ash[(wm * 64 + i * 16 + l16) * 64 + kk * 32 + quad * 8];
#pragma unroll
      for (int j = 0; j < 4; j++) bv[j] = *(const bf16x8*)&Bsh[(wn * 64 + j * 16 + l16) * 64 + kk * 32 + quad * 8];
#pragma unroll
      for (int i = 0; i < 4; i++)
#pragma unroll
        for (int j = 0; j < 4; j++)
          acc[i][j] = __builtin_amdgcn_mfma_f32_16x16x32_bf16(av[i], bv[j], acc[i][j], 0, 0, 0);
    }
  }

  const float* bias = ball + which * 256;
  const float scale = (which == 0) ? 0.25503486f : 1.0f;  // (1/sqrt(32))*log2(e) folded into Q
#pragma unroll
  for (int i = 0; i < 4; i++) {
#pragma unroll
    for (int j = 0; j < 4; j++) {
      const int mb = m0 + wm * 64 + i * 16 + quad * 4;
      const int n = n0 + wn * 64 + j * 16 + l16;
#pragma unroll
      for (int r = 0; r < 4; r++) {
        const int m = mb + r;
        float v = acc[i][j][r];
        if (which < 2) {
          v = (v + bias[n]) * scale;
          u16* D = (which ? Kb : Qb) + (size_t)b * 262144;
          D[(size_t)m * 256 + n] = f2bf(v);
        } else {
          v = v + bias[m];
          (Vb + (size_t)b * 262144)[(size_t)m * 1024 + n] = f2bf(v);
        }
      }
    }
  }
}

// ---------- fused attention v4: LDS-staged, 64 q-rows/wave, 256-t K-tiles ----------
// S^T = mfma32(K-frag, Q-frag): lane holds P[q=l16][t=quad*4+r] per 16x16 tile --
// exactly the B-frag of mfma_f32_16x16x16bf16_1k. No LDS round-trip for P.
// exp2 via builtin (no s_nop serialization); scale*log2e folded into Q.
// grid 1024 linear: blk = qc*256 + bh -> XCD = bh%8 (all 4 q-chunks of a (b,h)
// share an XCD -> K/V L2-resident).
__global__ void __launch_bounds__(256) attn_kernel(const u16* __restrict__ Q,
                                                   const u16* __restrict__ K,
                                                   const u16* __restrict__ V,
                                                   u16* __restrict__ O) {
  const int blk = blockIdx.x;
  const int qc = blk >> 8, bh = blk & 255;
  const int b = bh >> 3, h = bh & 7;
  const int tid = threadIdx.x, wave = tid >> 6, lane = tid & 63;
  const int quad = lane >> 4, l16 = lane & 15;
  __shared__ u16 Ksh[256 * 40];   // (t, d) pitch 40 u16
  __shared__ u16 Vsh[32 * 264];   // (d, t) pitch 264 u16
  const u16* Qg = Q + (size_t)b * 262144 + h * 32;
  const u16* Kg = K + (size_t)b * 262144 + h * 32;
  const u16* Vg = V + (size_t)b * 262144 + (size_t)h * 32768;
  const int qw = qc * 256 + wave * 64;   // this wave's 64 q rows

  bf16x8 qf[4];
#pragma unroll
  for (int qt = 0; qt < 4; qt++)
    qf[qt] = *(const bf16x8*)(Qg + (size_t)(qw + qt * 16 + l16) * 256 + quad * 8);

  f32x4 oacc[2][4];  // [dt][qt]: C[m=d][n=q]
#pragma unroll
  for (int dt = 0; dt < 2; dt++)
#pragma unroll
    for (int qt = 0; qt < 4; qt++) oacc[dt][qt] = (f32x4){0.f, 0.f, 0.f, 0.f};
  float lsum[4] = {0.f, 0.f, 0.f, 0.f};

  for (int kt0 = 0; kt0 < 1024; kt0 += 256) {
    __syncthreads();   // WAR: prior tile's frag reads done
    for (int c = tid; c < 1024; c += 256) {
      const int r = c >> 2, off = (c & 3) * 8;
      *(uint4*)&Ksh[r * 40 + off] = *(const uint4*)(Kg + (size_t)(kt0 + r) * 256 + off);
    }
    for (int c = tid; c < 1024; c += 256) {
      const int r = c >> 5, off = (c & 31) * 8;
      *(uint4*)&Vsh[r * 264 + off] = *(const uint4*)(Vg + (size_t)r * 1024 + kt0 + off);
    }
    __syncthreads();
#pragma unroll
    for (int sub = 0; sub < 8; sub++) {
      const int sk0 = sub * 32;
      bf16x4 pf[2][4];
#pragma unroll
      for (int mt = 0; mt < 2; mt++) {
        const bf16x8 kf = *(const bf16x8*)&Ksh[(sk0 + mt * 16 + l16) * 40 + quad * 8];
        f32x4 sf[4];
#pragma unroll
        for (int qt = 0; qt < 4; qt++)
          sf[qt] = __builtin_amdgcn_mfma_f32_16x16x32_bf16(
              kf, qf[qt], (f32x4){0.f, 0.f, 0.f, 0.f}, 0, 0, 0);
#pragma unroll
        for (int qt = 0; qt < 4; qt++) {
          const float p0 = __builtin_amdgcn_exp2f(sf[qt][0]);
          const float p1 = __builtin_amdgcn_exp2f(sf[qt][1]);
          const float p2 = __builtin_amdgcn_exp2f(sf[qt][2]);
          const float p3 = __builtin_amdgcn_exp2f(sf[qt][3]);
          lsum[qt] += (p0 + p1) + (p2 + p3);
          union { u32 u[2]; bf16x4 v; } pv;
          pv.u[0] = __builtin_amdgcn_perm(fbits(p1), fbits(p0), 0x07060302u);
          pv.u[1] = __builtin_amdgcn_perm(fbits(p3), fbits(p2), 0x07060302u);
          pf[mt][qt] = pv.v;
        }
      }
      bf16x4 vf[2][2];
#pragma unroll
      for (int dt = 0; dt < 2; dt++)
#pragma unroll
        for (int mt = 0; mt < 2; mt++)
          vf[dt][mt] = *(const bf16x4*)&Vsh[(dt * 16 + l16) * 264 + sk0 + mt * 16 + quad * 4];
#pragma unroll
      for (int mt = 0; mt < 2; mt++)
#pragma unroll
        for (int dt = 0; dt < 2; dt++)
#pragma unroll
          for (int qt = 0; qt < 4; qt++)
            oacc[dt][qt] = __builtin_amdgcn_mfma_f32_16x16x16bf16_1k(
                vf[dt][mt], pf[mt][qt], oacc[dt][qt], 0, 0, 0);
    }
  }

  float linv[4];
#pragma unroll
  for (int qt = 0; qt < 4; qt++) {
    float l = lsum[qt];
    l += __shfl_xor(l, 16);
    l += __shfl_xor(l, 32);
    linv[qt] = 1.0f / l;
  }
#pragma unroll
  for (int dt = 0; dt < 2; dt++)
#pragma unroll
    for (int qt = 0; qt < 4; qt++) {
      ushort4 st;
      st.x = f2bf(oacc[dt][qt][0] * linv[qt]);
      st.y = f2bf(oacc[dt][qt][1] * linv[qt]);
      st.z = f2bf(oacc[dt][qt][2] * linv[qt]);
      st.w = f2bf(oacc[dt][qt][3] * linv[qt]);
      *(ushort4*)(O + (size_t)(b * 1024 + qw + qt * 16 + l16) * 256 + h * 32 + dt * 16 + quad * 4) = st;
    }
}

// ---------- out projection + residual, BK=64: out = 2x + g*(Wo.O + bo) ----------
__global__ void __launch_bounds__(256) out_gemm(const u16* __restrict__ WoB,
                                                const float* __restrict__ bg,
                                                const u16* __restrict__ Ob,
                                                const void* __restrict__ xin,
                                                void* __restrict__ outp,
                                                const u32* __restrict__ xdet) {
  const int b = blockIdx.z;
  const int m0 = blockIdx.y * 128, n0 = blockIdx.x * 128;
  const int tid = threadIdx.x, lane = tid & 63, wave = tid >> 6;
  const int quad = lane >> 4, l16 = lane & 15;
  const int wm = wave >> 1, wn = wave & 1;
  const int isbf = detect_bf16(xdet);
  const u16* Bb = Ob + (size_t)b * 262144;
  __shared__ u16 Ash[8192], Bsh[8192];
  f32x4 acc[4][4];
#pragma unroll
  for (int i = 0; i < 4; i++)
#pragma unroll
    for (int j = 0; j < 4; j++) acc[i][j] = (f32x4){0.f, 0.f, 0.f, 0.f};

  const int srow = lane >> 3, scol = (lane & 7) * 8;
  for (int k0 = 0; k0 < 256; k0 += 64) {
    __syncthreads();
#pragma unroll
    for (int p = 0; p < 4; p++) {
      const int row = p * 32 + wave * 8;
      gld16(WoB + (size_t)(m0 + row + srow) * 256 + k0 + scol, &Ash[row * 64 + lane * 8]);
      gld16(Bb  + (size_t)(n0 + row + srow) * 256 + k0 + scol, &Bsh[row * 64 + lane * 8]);
    }
    __syncthreads();
#pragma unroll
    for (int kk = 0; kk < 2; kk++) {
      bf16x8 av[4], bv[4];
#pragma unroll
      for (int i = 0; i < 4; i++) av[i] = *(const bf16x8*)&Ash[(wm * 64 + i * 16 + l16) * 64 + kk * 32 + quad * 8];
#pragma unroll
      for (int j = 0; j < 4; j++) bv[j] = *(const bf16x8*)&Bsh[(wn * 64 + j * 16 + l16) * 64 + kk * 32 + quad * 8];
#pragma unroll
      for (int i = 0; i < 4; i++)
#pragma unroll
        for (int j = 0; j < 4; j++)
          acc[i][j] = __builtin_amdgcn_mfma_f32_16x16x32_bf16(av[i], bv[j], acc[i][j], 0, 0, 0);
    }
  }

  const float g = bg[256];
#pragma unroll
  for (int i = 0; i < 4; i++) {
#pragma unroll
    for (int j = 0; j < 4; j++) {
      const int mb = m0 + wm * 64 + i * 16 + quad * 4;
      const int n = n0 + wn * 64 + j * 16 + l16;
#pragma unroll
      for (int r = 0; r < 4; r++) {
        const int m = mb + r;
        const float v = acc[i][j][r] + bg[m];
        const size_t gi = (size_t)b * 262144 + (size_t)m * 1024 + n;
        const float xv = isbf ? bf2f(((const u16*)xin)[gi]) : ((const float*)xin)[gi];
        const float res = 2.f * xv + g * v;
        if (isbf) ((u16*)outp)[gi] = f2bf(res);
        else      ((float*)outp)[gi] = res;
      }
    }
  }
}

// ---------- launcher ----------
extern "C" void kernel_launch(void* const* d_in, const int* in_sizes, int n_in,
                              void* d_out, int out_size, void* d_ws, size_t ws_size,
                              hipStream_t stream) {
  const void* x  = d_in[0];
  const void* Wq = d_in[1]; const void* bq = d_in[2];
  const void* Wk = d_in[3]; const void* bk = d_in[4];
  const void* Wv = d_in[5]; const void* bv = d_in[6];
  const void* Wo = d_in[7]; const void* bo = d_in[8];
  const void* gm = d_in[9];

  u16* ws = (u16*)d_ws;
  u16* xT = ws;            // (b,s,c) bf16; reused as O after V-proj
  u16* Qb = ws + NT;       // (b,s,256), scale*log2e folded
  u16* Kb = ws + 2 * NT;   // (b,s,256)
  u16* Vb = ws + 3 * NT;   // (b,256,s)
  u16* Ob = xT;
  const u32* xdet = (const u32*)x;

  // d_out doubles as QKV-weight scratch until out_gemm rewrites it fully
  u16* WqkvB = (u16*)d_out;                              // 3 x 65536 u16
  float* bqkvF = (float*)((u16*)d_out + 196608);         // 768 f32

  // Wo scratch: ws tail if it fits (prep folded into prologue), else dead-Q fallback
  const bool tail = ws_size >= (size_t)(4 * NT + 66048) * 2;
  u16* WoB = tail ? (ws + 4 * NT) : Qb;
  float* boF = tail ? (float*)(ws + 4 * NT + 65536) : (float*)(Qb + 65536);

  prologue_kernel<<<dim3(tail ? 2304 : 2240), 256, 0, stream>>>(
      x, xT, Wq, Wk, Wv, bq, bk, bv, WqkvB, bqkvF, Wo, bo, gm, WoB, boF);
  qkv_gemm<<<dim3(2, 8, 96), 256, 0, stream>>>(xT, WqkvB, bqkvF, Qb, Kb, Vb);
  attn_kernel<<<dim3(1024), 256, 0, stream>>>(Qb, Kb, Vb, Ob);
  if (!tail) prep_o<<<dim3(64), 256, 0, stream>>>(Wo, bo, gm, WoB, boF, xdet);
  out_gemm<<<dim3(8, 2, 32), 256, 0, stream>>>(WoB, boF, Ob, x, d_out, xdet);
}

// Round 5
// 231.740 us; speedup vs baseline: 1.1832x; 1.1832x over previous
//
#include <hip/hip_runtime.h>
#include <stdint.h>

typedef unsigned short u16;
typedef unsigned int   u32;
typedef __attribute__((ext_vector_type(8))) short bf16x8;  // 8 bf16 = 4 VGPR
typedef __attribute__((ext_vector_type(4))) short bf16x4;  // 4 bf16 = 2 VGPR
typedef __attribute__((ext_vector_type(4))) float f32x4;   // MFMA C/D frag

#define NT ((size_t)8388608)   // 32*1024*256 elements

// ---------- helpers ----------
__device__ __forceinline__ float bf2f(u16 u) {
  union { float f; u32 i; } v; v.i = ((u32)u) << 16; return v.f;
}
__device__ __forceinline__ u16 f2bf(float f) {
  union { float f; u32 i; } v; v.f = f;
  u32 r = (v.i + 0x7fffu + ((v.i >> 16) & 1u)) >> 16;   // RNE
  return (u16)r;
}
__device__ __forceinline__ u32 fbits(float f) {
  union { float f; u32 i; } v; v.f = f; return v.i;
}
// bf16-vs-f32 buffer sniff (64-lane ballot on exponent-byte position)
__device__ __forceinline__ int detect_bf16(const u32* __restrict__ xd) {
  u32 w = xd[threadIdx.x & 63];
  u32 e = (w >> 8) & 0x7fu;
  unsigned long long m = __ballot((e >= 0x38u) && (e <= 0x41u));
  return __popcll(m) > 32;
}
// async 16B/lane global->LDS (dest = wave-uniform base + lane*16)
__device__ __forceinline__ void gld16(const void* g, void* l) {
  __builtin_amdgcn_global_load_lds((const __attribute__((address_space(1))) u32*)g,
                                   (__attribute__((address_space(3))) u32*)l, 16, 0, 0);
}

// ---------- prologue: x transpose (0..2047) + Wq/Wk/Wv prep (2048..2239) + optional Wo (2240..2303) ----------
__global__ void __launch_bounds__(256) prologue_kernel(const void* __restrict__ xin,
                                                       u16* __restrict__ xT,
                                                       const void* __restrict__ W0, const void* __restrict__ W1,
                                                       const void* __restrict__ W2, const void* __restrict__ b0,
                                                       const void* __restrict__ b1, const void* __restrict__ b2,
                                                       u16* __restrict__ wdst, float* __restrict__ bdst,
                                                       const void* __restrict__ Wo, const void* __restrict__ bo,
                                                       const void* __restrict__ gm, u16* __restrict__ wodst,
                                                       float* __restrict__ bodst) {
  const int blk = blockIdx.x;
  const int tid = threadIdx.x;
  const int isbf = detect_bf16((const u32*)xin);
  if (blk < 2048) {
    const int s0 = (blk & 15) * 64, c0 = ((blk >> 4) & 3) * 64, b = blk >> 6;
    __shared__ u16 T[64][72];  // [c-local][s-local], +8 pad
    if (isbf) {
      const u16* xp = (const u16*)xin;
      for (int t = tid; t < 512; t += 256) {
        int r = t >> 3, off = (t & 7) * 8;
        *(uint4*)&T[r][off] = *(const uint4*)(xp + ((size_t)(b * 256 + c0 + r)) * 1024 + s0 + off);
      }
    } else {
      const float* xp = (const float*)xin;
      for (int t = tid; t < 512; t += 256) {
        int r = t >> 3, off = (t & 7) * 8;
        const float* s = xp + ((size_t)(b * 256 + c0 + r)) * 1024 + s0 + off;
#pragma unroll
        for (int u = 0; u < 8; u++) T[r][off + u] = f2bf(s[u]);
      }
    }
    __syncthreads();
    for (int t = tid; t < 512; t += 256) {
      int r = t >> 3, off = (t & 7) * 8;   // r = s-local, off = c-local
      union { u16 h[8]; uint4 v; } pk;
#pragma unroll
      for (int u = 0; u < 8; u++) pk.h[u] = T[off + u][r];
      *(uint4*)(xT + ((size_t)(b * 1024 + s0 + r)) * 256 + c0 + off) = pk.v;
    }
  } else if (blk < 2240) {
    const int g = blk - 2048;            // 192 blocks: 64 per weight
    const int which = g >> 6, bk = g & 63;
    const void* Ws = which == 0 ? W0 : which == 1 ? W1 : W2;
    const void* bs = which == 0 ? b0 : which == 1 ? b1 : b2;
    const int idx = bk * 1024 + tid * 4;
    u16* dst = wdst + which * 65536 + idx;
    if (isbf) {
      *(ushort4*)dst = *(const ushort4*)((const u16*)Ws + idx);
    } else {
      const float* s = (const float*)Ws + idx;
      ushort4 o; o.x = f2bf(s[0]); o.y = f2bf(s[1]); o.z = f2bf(s[2]); o.w = f2bf(s[3]);
      *(ushort4*)dst = o;
    }
    if (bk == 0) {
      bdst[which * 256 + tid] = isbf ? bf2f(((const u16*)bs)[tid]) : ((const float*)bs)[tid];
    }
  } else {
    const int g = blk - 2240;            // 64 blocks: Wo
    const int idx = g * 1024 + tid * 4;
    if (isbf) {
      *(ushort4*)(wodst + idx) = *(const ushort4*)((const u16*)Wo + idx);
    } else {
      const float* s = (const float*)Wo + idx;
      ushort4 o; o.x = f2bf(s[0]); o.y = f2bf(s[1]); o.z = f2bf(s[2]); o.w = f2bf(s[3]);
      *(ushort4*)(wodst + idx) = o;
    }
    if (g == 0) {
      bodst[tid] = isbf ? bf2f(((const u16*)bo)[tid]) : ((const float*)bo)[tid];
      if (tid == 0) bodst[256] = isbf ? bf2f(((const u16*)gm)[0]) : ((const float*)gm)[0];
    }
  }
}

// ---------- Wo prep fallback (when ws tail unavailable; runs after attn) ----------
__global__ void __launch_bounds__(256) prep_o(const void* __restrict__ Wo, const void* __restrict__ bo,
                                              const void* __restrict__ gm, u16* __restrict__ wdst,
                                              float* __restrict__ bdst, const u32* __restrict__ xdet) {
  const int isbf = detect_bf16(xdet);
  const int idx = blockIdx.x * 1024 + threadIdx.x * 4;
  if (isbf) {
    *(ushort4*)(wdst + idx) = *(const ushort4*)((const u16*)Wo + idx);
  } else {
    const float* s = (const float*)Wo + idx;
    ushort4 o; o.x = f2bf(s[0]); o.y = f2bf(s[1]); o.z = f2bf(s[2]); o.w = f2bf(s[3]);
    *(ushort4*)(wdst + idx) = o;
  }
  if (blockIdx.x == 0) {
    int t = threadIdx.x;
    bdst[t] = isbf ? bf2f(((const u16*)bo)[t]) : ((const float*)bo)[t];
    if (t == 0) bdst[256] = isbf ? bf2f(((const u16*)gm)[0]) : ((const float*)gm)[0];
  }
}

// ---------- fused QKV projection, BK=64: one launch, z = b*3 + which ----------
__global__ void __launch_bounds__(256) qkv_gemm(const u16* __restrict__ xT,
                                                const u16* __restrict__ Wall,
                                                const float* __restrict__ ball,
                                                u16* __restrict__ Qb, u16* __restrict__ Kb,
                                                u16* __restrict__ Vb) {
  const int z = blockIdx.z, b = z / 3, which = z - b * 3;
  const int tid = threadIdx.x, lane = tid & 63, wave = tid >> 6;
  const int quad = lane >> 4, l16 = lane & 15;
  const int wm = wave >> 1, wn = wave & 1;
  const u16* xb = xT + (size_t)b * 262144;
  const u16* W = Wall + which * 65536;
  int m0, n0; const u16 *Abase, *Bbase;
  if (which < 2) { m0 = blockIdx.y * 128; n0 = blockIdx.x * 128; Abase = xb; Bbase = W; }
  else           { m0 = blockIdx.x * 128; n0 = blockIdx.y * 128; Abase = W; Bbase = xb; }

  __shared__ u16 Ash[8192], Bsh[8192];   // 128 rows x 64 (128B rows)
  f32x4 acc[4][4];
#pragma unroll
  for (int i = 0; i < 4; i++)
#pragma unroll
    for (int j = 0; j < 4; j++) acc[i][j] = (f32x4){0.f, 0.f, 0.f, 0.f};

  const int srow = lane >> 3, scol = (lane & 7) * 8;
  for (int k0 = 0; k0 < 256; k0 += 64) {
    __syncthreads();   // WAR: prior frag reads done before restage lands
#pragma unroll
    for (int p = 0; p < 4; p++) {
      const int row = p * 32 + wave * 8;
      gld16(Abase + (size_t)(m0 + row + srow) * 256 + k0 + scol, &Ash[row * 64 + lane * 8]);
      gld16(Bbase + (size_t)(n0 + row + srow) * 256 + k0 + scol, &Bsh[row * 64 + lane * 8]);
    }
    __syncthreads();   // drains vmcnt before barrier
#pragma unroll
    for (int kk = 0; kk < 2; kk++) {
      bf16x8 av[4], bv[4];
#pragma unroll
      for (int i = 0; i < 4; i++) av[i] = *(const bf16x8*)&Ash[(wm * 64 + i * 16 + l16) * 64 + kk * 32 + quad * 8];
#pragma unroll
      for (int j = 0; j < 4; j++) bv[j] = *(const bf16x8*)&Bsh[(wn * 64 + j * 16 + l16) * 64 + kk * 32 + quad * 8];
#pragma unroll
      for (int i = 0; i < 4; i++)
#pragma unroll
        for (int j = 0; j < 4; j++)
          acc[i][j] = __builtin_amdgcn_mfma_f32_16x16x32_bf16(av[i], bv[j], acc[i][j], 0, 0, 0);
    }
  }

  const float* bias = ball + which * 256;
  const float scale = (which == 0) ? 0.25503486f : 1.0f;  // (1/sqrt(32))*log2(e) folded into Q
#pragma unroll
  for (int i = 0; i < 4; i++) {
#pragma unroll
    for (int j = 0; j < 4; j++) {
      const int mb = m0 + wm * 64 + i * 16 + quad * 4;
      const int n = n0 + wn * 64 + j * 16 + l16;
#pragma unroll
      for (int r = 0; r < 4; r++) {
        const int m = mb + r;
        float v = acc[i][j][r];
        if (which < 2) {
          v = (v + bias[n]) * scale;
          u16* D = (which ? Kb : Qb) + (size_t)b * 262144;
          D[(size_t)m * 256 + n] = f2bf(v);
        } else {
          v = v + bias[m];
          (Vb + (size_t)b * 262144)[(size_t)m * 1024 + n] = f2bf(v);
        }
      }
    }
  }
}

// ---------- fused attention v5: 32 q-rows/wave (VGPR-lean), 256-t K-tiles, gld16 K ----------
// S^T = mfma32(K-frag, Q-frag): lane holds P[q=l16][t=quad*4+r] per 16x16 tile --
// exactly the B-frag of mfma_f32_16x16x16bf16_1k. No LDS round-trip for P.
// exp2 builtin; (1/sqrt(32))*log2(e) folded into Q. grid 2048 linear:
// blk = qc*256 + bh -> XCD = bh%8 (all 8 q-chunks of a (b,h) share an XCD).
__global__ void __launch_bounds__(256) attn_kernel(const u16* __restrict__ Q,
                                                   const u16* __restrict__ K,
                                                   const u16* __restrict__ V,
                                                   u16* __restrict__ O) {
  const int blk = blockIdx.x;
  const int qc = blk >> 8, bh = blk & 255;
  const int b = bh >> 3, h = bh & 7;
  const int tid = threadIdx.x, wave = tid >> 6, lane = tid & 63;
  const int quad = lane >> 4, l16 = lane & 15;
  __shared__ u16 Ksh[256 * 32];   // (t, d) 64B rows, unpadded (gld16 dest)
  __shared__ u16 Vsh[32 * 264];   // (d, t) pitch 264 u16, manual staged
  const u16* Qg = Q + (size_t)b * 262144 + h * 32;
  const u16* Kg = K + (size_t)b * 262144 + h * 32;
  const u16* Vg = V + (size_t)b * 262144 + (size_t)h * 32768;
  const int qw = qc * 128 + wave * 32;   // this wave's 32 q rows

  bf16x8 qf[2];
#pragma unroll
  for (int qt = 0; qt < 2; qt++)
    qf[qt] = *(const bf16x8*)(Qg + (size_t)(qw + qt * 16 + l16) * 256 + quad * 8);

  f32x4 oacc[2][2];  // [dt][qt]: C[m=d][n=q]
#pragma unroll
  for (int dt = 0; dt < 2; dt++)
#pragma unroll
    for (int qt = 0; qt < 2; qt++) oacc[dt][qt] = (f32x4){0.f, 0.f, 0.f, 0.f};
  float lsum[2] = {0.f, 0.f};

  const int krow = lane >> 2, kcol = (lane & 3) * 8;   // K staging: 4 lanes/row
  for (int kt0 = 0; kt0 < 1024; kt0 += 256) {
    __syncthreads();   // WAR: prior tile's frag reads done
#pragma unroll
    for (int i = 0; i < 4; i++) {
      const int rb = wave * 64 + i * 16;
      gld16(Kg + (size_t)(kt0 + rb + krow) * 256 + kcol, &Ksh[rb * 32 + lane * 8]);
    }
    for (int c = tid; c < 1024; c += 256) {
      const int r = c >> 5, off = (c & 31) * 8;
      *(uint4*)&Vsh[r * 264 + off] = *(const uint4*)(Vg + (size_t)r * 1024 + kt0 + off);
    }
    __syncthreads();   // drains vmcnt (gld16) + lgkm before barrier
#pragma unroll
    for (int sub = 0; sub < 8; sub++) {
      const int sk0 = sub * 32;
      bf16x4 pf[2][2];
#pragma unroll
      for (int mt = 0; mt < 2; mt++) {
        const bf16x8 kf = *(const bf16x8*)&Ksh[(sk0 + mt * 16 + l16) * 32 + quad * 8];
        f32x4 sf[2];
#pragma unroll
        for (int qt = 0; qt < 2; qt++)
          sf[qt] = __builtin_amdgcn_mfma_f32_16x16x32_bf16(
              kf, qf[qt], (f32x4){0.f, 0.f, 0.f, 0.f}, 0, 0, 0);
#pragma unroll
        for (int qt = 0; qt < 2; qt++) {
          const float p0 = __builtin_amdgcn_exp2f(sf[qt][0]);
          const float p1 = __builtin_amdgcn_exp2f(sf[qt][1]);
          const float p2 = __builtin_amdgcn_exp2f(sf[qt][2]);
          const float p3 = __builtin_amdgcn_exp2f(sf[qt][3]);
          lsum[qt] += (p0 + p1) + (p2 + p3);
          union { u32 u[2]; bf16x4 v; } pv;
          pv.u[0] = __builtin_amdgcn_perm(fbits(p1), fbits(p0), 0x07060302u);
          pv.u[1] = __builtin_amdgcn_perm(fbits(p3), fbits(p2), 0x07060302u);
          pf[mt][qt] = pv.v;
        }
      }
      bf16x4 vf[2][2];
#pragma unroll
      for (int dt = 0; dt < 2; dt++)
#pragma unroll
        for (int mt = 0; mt < 2; mt++)
          vf[dt][mt] = *(const bf16x4*)&Vsh[(dt * 16 + l16) * 264 + sk0 + mt * 16 + quad * 4];
#pragma unroll
      for (int mt = 0; mt < 2; mt++)
#pragma unroll
        for (int dt = 0; dt < 2; dt++)
#pragma unroll
          for (int qt = 0; qt < 2; qt++)
            oacc[dt][qt] = __builtin_amdgcn_mfma_f32_16x16x16bf16_1k(
                vf[dt][mt], pf[mt][qt], oacc[dt][qt], 0, 0, 0);
    }
  }

  float linv[2];
#pragma unroll
  for (int qt = 0; qt < 2; qt++) {
    float l = lsum[qt];
    l += __shfl_xor(l, 16);
    l += __shfl_xor(l, 32);
    linv[qt] = 1.0f / l;
  }
#pragma unroll
  for (int dt = 0; dt < 2; dt++)
#pragma unroll
    for (int qt = 0; qt < 2; qt++) {
      ushort4 st;
      st.x = f2bf(oacc[dt][qt][0] * linv[qt]);
      st.y = f2bf(oacc[dt][qt][1] * linv[qt]);
      st.z = f2bf(oacc[dt][qt][2] * linv[qt]);
      st.w = f2bf(oacc[dt][qt][3] * linv[qt]);
      *(ushort4*)(O + (size_t)(b * 1024 + qw + qt * 16 + l16) * 256 + h * 32 + dt * 16 + quad * 4) = st;
    }
}

// ---------- out projection + residual, BK=64: out = 2x + g*(Wo.O + bo) ----------
__global__ void __launch_bounds__(256) out_gemm(const u16* __restrict__ WoB,
                                                const float* __restrict__ bg,
                                                const u16* __restrict__ Ob,
                                                const void* __restrict__ xin,
                                                void* __restrict__ outp,
                                                const u32* __restrict__ xdet) {
  const int b = blockIdx.z;
  const int m0 = blockIdx.y * 128, n0 = blockIdx.x * 128;
  const int tid = threadIdx.x, lane = tid & 63, wave = tid >> 6;
  const int quad = lane >> 4, l16 = lane & 15;
  const int wm = wave >> 1, wn = wave & 1;
  const int isbf = detect_bf16(xdet);
  const u16* Bb = Ob + (size_t)b * 262144;
  __shared__ u16 Ash[8192], Bsh[8192];
  f32x4 acc[4][4];
#pragma unroll
  for (int i = 0; i < 4; i++)
#pragma unroll
    for (int j = 0; j < 4; j++) acc[i][j] = (f32x4){0.f, 0.f, 0.f, 0.f};

  const int srow = lane >> 3, scol = (lane & 7) * 8;
  for (int k0 = 0; k0 < 256; k0 += 64) {
    __syncthreads();
#pragma unroll
    for (int p = 0; p < 4; p++) {
      const int row = p * 32 + wave * 8;
      gld16(WoB + (size_t)(m0 + row + srow) * 256 + k0 + scol, &Ash[row * 64 + lane * 8]);
      gld16(Bb  + (size_t)(n0 + row + srow) * 256 + k0 + scol, &Bsh[row * 64 + lane * 8]);
    }
    __syncthreads();
#pragma unroll
    for (int kk = 0; kk < 2; kk++) {
      bf16x8 av[4], bv[4];
#pragma unroll
      for (int i = 0; i < 4; i++) av[i] = *(const bf16x8*)&Ash[(wm * 64 + i * 16 + l16) * 64 + kk * 32 + quad * 8];
#pragma unroll
      for (int j = 0; j < 4; j++) bv[j] = *(const bf16x8*)&Bsh[(wn * 64 + j * 16 + l16) * 64 + kk * 32 + quad * 8];
#pragma unroll
      for (int i = 0; i < 4; i++)
#pragma unroll
        for (int j = 0; j < 4; j++)
          acc[i][j] = __builtin_amdgcn_mfma_f32_16x16x32_bf16(av[i], bv[j], acc[i][j], 0, 0, 0);
    }
  }

  const float g = bg[256];
#pragma unroll
  for (int i = 0; i < 4; i++) {
#pragma unroll
    for (int j = 0; j < 4; j++) {
      const int mb = m0 + wm * 64 + i * 16 + quad * 4;
      const int n = n0 + wn * 64 + j * 16 + l16;
#pragma unroll
      for (int r = 0; r < 4; r++) {
        const int m = mb + r;
        const float v = acc[i][j][r] + bg[m];
        const size_t gi = (size_t)b * 262144 + (size_t)m * 1024 + n;
        const float xv = isbf ? bf2f(((const u16*)xin)[gi]) : ((const float*)xin)[gi];
        const float res = 2.f * xv + g * v;
        if (isbf) ((u16*)outp)[gi] = f2bf(res);
        else      ((float*)outp)[gi] = res;
      }
    }
  }
}

// ---------- launcher ----------
extern "C" void kernel_launch(void* const* d_in, const int* in_sizes, int n_in,
                              void* d_out, int out_size, void* d_ws, size_t ws_size,
                              hipStream_t stream) {
  const void* x  = d_in[0];
  const void* Wq = d_in[1]; const void* bq = d_in[2];
  const void* Wk = d_in[3]; const void* bk = d_in[4];
  const void* Wv = d_in[5]; const void* bv = d_in[6];
  const void* Wo = d_in[7]; const void* bo = d_in[8];
  const void* gm = d_in[9];

  u16* ws = (u16*)d_ws;
  u16* xT = ws;            // (b,s,c) bf16; reused as O after V-proj
  u16* Qb = ws + NT;       // (b,s,256), scale*log2e folded
  u16* Kb = ws + 2 * NT;   // (b,s,256)
  u16* Vb = ws + 3 * NT;   // (b,256,s)
  u16* Ob = xT;
  const u32* xdet = (const u32*)x;

  // d_out doubles as QKV-weight scratch until out_gemm rewrites it fully
  u16* WqkvB = (u16*)d_out;                              // 3 x 65536 u16
  float* bqkvF = (float*)((u16*)d_out + 196608);         // 768 f32

  // Wo scratch: ws tail if it fits (prep folded into prologue), else dead-Q fallback
  const bool tail = ws_size >= (size_t)(4 * NT + 66048) * 2;
  u16* WoB = tail ? (ws + 4 * NT) : Qb;
  float* boF = tail ? (float*)(ws + 4 * NT + 65536) : (float*)(Qb + 65536);

  prologue_kernel<<<dim3(tail ? 2304 : 2240), 256, 0, stream>>>(
      x, xT, Wq, Wk, Wv, bq, bk, bv, WqkvB, bqkvF, Wo, bo, gm, WoB, boF);
  qkv_gemm<<<dim3(2, 8, 96), 256, 0, stream>>>(xT, WqkvB, bqkvF, Qb, Kb, Vb);
  attn_kernel<<<dim3(2048), 256, 0, stream>>>(Qb, Kb, Vb, Ob);
  if (!tail) prep_o<<<dim3(64), 256, 0, stream>>>(Wo, bo, gm, WoB, boF, xdet);
  out_gemm<<<dim3(8, 2, 32), 256, 0, stream>>>(WoB, boF, Ob, x, d_out, xdet);
}

// Round 6
// 223.007 us; speedup vs baseline: 1.2295x; 1.0392x over previous
//
#include <hip/hip_runtime.h>
#include <stdint.h>

typedef unsigned short u16;
typedef unsigned int   u32;
typedef __attribute__((ext_vector_type(8))) short bf16x8;  // 8 bf16 = 4 VGPR
typedef __attribute__((ext_vector_type(4))) short bf16x4;  // 4 bf16 = 2 VGPR
typedef __attribute__((ext_vector_type(4))) float f32x4;   // MFMA C/D frag

#define NT ((size_t)8388608)   // 32*1024*256 elements

// ---------- helpers ----------
__device__ __forceinline__ float bf2f(u16 u) {
  union { float f; u32 i; } v; v.i = ((u32)u) << 16; return v.f;
}
__device__ __forceinline__ u16 f2bf(float f) {
  union { float f; u32 i; } v; v.f = f;
  u32 r = (v.i + 0x7fffu + ((v.i >> 16) & 1u)) >> 16;   // RNE
  return (u16)r;
}
__device__ __forceinline__ u32 fbits(float f) {
  union { float f; u32 i; } v; v.f = f; return v.i;
}
// bf16-vs-f32 buffer sniff (64-lane ballot on exponent-byte position)
__device__ __forceinline__ int detect_bf16(const u32* __restrict__ xd) {
  u32 w = xd[threadIdx.x & 63];
  u32 e = (w >> 8) & 0x7fu;
  unsigned long long m = __ballot((e >= 0x38u) && (e <= 0x41u));
  return __popcll(m) > 32;
}
// async 16B/lane global->LDS (dest = wave-uniform base + lane*16)
__device__ __forceinline__ void gld16(const void* g, void* l) {
  __builtin_amdgcn_global_load_lds((const __attribute__((address_space(1))) u32*)g,
                                   (__attribute__((address_space(3))) u32*)l, 16, 0, 0);
}

// ---------- prologue: x transpose (0..2047) + Wq/Wk/Wv prep (2048..2239) + optional Wo (2240..2303) ----------
__global__ void __launch_bounds__(256) prologue_kernel(const void* __restrict__ xin,
                                                       u16* __restrict__ xT,
                                                       const void* __restrict__ W0, const void* __restrict__ W1,
                                                       const void* __restrict__ W2, const void* __restrict__ b0,
                                                       const void* __restrict__ b1, const void* __restrict__ b2,
                                                       u16* __restrict__ wdst, float* __restrict__ bdst,
                                                       const void* __restrict__ Wo, const void* __restrict__ bo,
                                                       const void* __restrict__ gm, u16* __restrict__ wodst,
                                                       float* __restrict__ bodst) {
  const int blk = blockIdx.x;
  const int tid = threadIdx.x;
  const int isbf = detect_bf16((const u32*)xin);
  if (blk < 2048) {
    const int s0 = (blk & 15) * 64, c0 = ((blk >> 4) & 3) * 64, b = blk >> 6;
    __shared__ u16 T[64][72];  // [c-local][s-local], +8 pad
    if (isbf) {
      const u16* xp = (const u16*)xin;
      for (int t = tid; t < 512; t += 256) {
        int r = t >> 3, off = (t & 7) * 8;
        *(uint4*)&T[r][off] = *(const uint4*)(xp + ((size_t)(b * 256 + c0 + r)) * 1024 + s0 + off);
      }
    } else {
      const float* xp = (const float*)xin;
      for (int t = tid; t < 512; t += 256) {
        int r = t >> 3, off = (t & 7) * 8;
        const float* s = xp + ((size_t)(b * 256 + c0 + r)) * 1024 + s0 + off;
#pragma unroll
        for (int u = 0; u < 8; u++) T[r][off + u] = f2bf(s[u]);
      }
    }
    __syncthreads();
    for (int t = tid; t < 512; t += 256) {
      int r = t >> 3, off = (t & 7) * 8;   // r = s-local, off = c-local
      union { u16 h[8]; uint4 v; } pk;
#pragma unroll
      for (int u = 0; u < 8; u++) pk.h[u] = T[off + u][r];
      *(uint4*)(xT + ((size_t)(b * 1024 + s0 + r)) * 256 + c0 + off) = pk.v;
    }
  } else if (blk < 2240) {
    const int g = blk - 2048;            // 192 blocks: 64 per weight
    const int which = g >> 6, bk = g & 63;
    const void* Ws = which == 0 ? W0 : which == 1 ? W1 : W2;
    const void* bs = which == 0 ? b0 : which == 1 ? b1 : b2;
    const int idx = bk * 1024 + tid * 4;
    u16* dst = wdst + which * 65536 + idx;
    if (isbf) {
      *(ushort4*)dst = *(const ushort4*)((const u16*)Ws + idx);
    } else {
      const float* s = (const float*)Ws + idx;
      ushort4 o; o.x = f2bf(s[0]); o.y = f2bf(s[1]); o.z = f2bf(s[2]); o.w = f2bf(s[3]);
      *(ushort4*)dst = o;
    }
    if (bk == 0) {
      bdst[which * 256 + tid] = isbf ? bf2f(((const u16*)bs)[tid]) : ((const float*)bs)[tid];
    }
  } else {
    const int g = blk - 2240;            // 64 blocks: Wo
    const int idx = g * 1024 + tid * 4;
    if (isbf) {
      *(ushort4*)(wodst + idx) = *(const ushort4*)((const u16*)Wo + idx);
    } else {
      const float* s = (const float*)Wo + idx;
      ushort4 o; o.x = f2bf(s[0]); o.y = f2bf(s[1]); o.z = f2bf(s[2]); o.w = f2bf(s[3]);
      *(ushort4*)(wodst + idx) = o;
    }
    if (g == 0) {
      bodst[tid] = isbf ? bf2f(((const u16*)bo)[tid]) : ((const float*)bo)[tid];
      if (tid == 0) bodst[256] = isbf ? bf2f(((const u16*)gm)[0]) : ((const float*)gm)[0];
    }
  }
}

// ---------- Wo prep fallback (when ws tail unavailable; runs after attn) ----------
__global__ void __launch_bounds__(256) prep_o(const void* __restrict__ Wo, const void* __restrict__ bo,
                                              const void* __restrict__ gm, u16* __restrict__ wdst,
                                              float* __restrict__ bdst, const u32* __restrict__ xdet) {
  const int isbf = detect_bf16(xdet);
  const int idx = blockIdx.x * 1024 + threadIdx.x * 4;
  if (isbf) {
    *(ushort4*)(wdst + idx) = *(const ushort4*)((const u16*)Wo + idx);
  } else {
    const float* s = (const float*)Wo + idx;
    ushort4 o; o.x = f2bf(s[0]); o.y = f2bf(s[1]); o.z = f2bf(s[2]); o.w = f2bf(s[3]);
    *(ushort4*)(wdst + idx) = o;
  }
  if (blockIdx.x == 0) {
    int t = threadIdx.x;
    bdst[t] = isbf ? bf2f(((const u16*)bo)[t]) : ((const float*)bo)[t];
    if (t == 0) bdst[256] = isbf ? bf2f(((const u16*)gm)[0]) : ((const float*)gm)[0];
  }
}

// ---------- fused QKV projection, BK=64: one launch, z = b*3 + which ----------
__global__ void __launch_bounds__(256) qkv_gemm(const u16* __restrict__ xT,
                                                const u16* __restrict__ Wall,
                                                const float* __restrict__ ball,
                                                u16* __restrict__ Qb, u16* __restrict__ Kb,
                                                u16* __restrict__ Vb) {
  const int z = blockIdx.z, b = z / 3, which = z - b * 3;
  const int tid = threadIdx.x, lane = tid & 63, wave = tid >> 6;
  const int quad = lane >> 4, l16 = lane & 15;
  const int wm = wave >> 1, wn = wave & 1;
  const u16* xb = xT + (size_t)b * 262144;
  const u16* W = Wall + which * 65536;
  int m0, n0; const u16 *Abase, *Bbase;
  if (which < 2) { m0 = blockIdx.y * 128; n0 = blockIdx.x * 128; Abase = xb; Bbase = W; }
  else           { m0 = blockIdx.x * 128; n0 = blockIdx.y * 128; Abase = W; Bbase = xb; }

  __shared__ u16 Ash[8192], Bsh[8192];   // 128 rows x 64 (128B rows)
  f32x4 acc[4][4];
#pragma unroll
  for (int i = 0; i < 4; i++)
#pragma unroll
    for (int j = 0; j < 4; j++) acc[i][j] = (f32x4){0.f, 0.f, 0.f, 0.f};

  const int srow = lane >> 3, scol = (lane & 7) * 8;
  for (int k0 = 0; k0 < 256; k0 += 64) {
    __syncthreads();   // WAR: prior frag reads done before restage lands
#pragma unroll
    for (int p = 0; p < 4; p++) {
      const int row = p * 32 + wave * 8;
      gld16(Abase + (size_t)(m0 + row + srow) * 256 + k0 + scol, &Ash[row * 64 + lane * 8]);
      gld16(Bbase + (size_t)(n0 + row + srow) * 256 + k0 + scol, &Bsh[row * 64 + lane * 8]);
    }
    __syncthreads();   // drains vmcnt before barrier
#pragma unroll
    for (int kk = 0; kk < 2; kk++) {
      bf16x8 av[4], bv[4];
#pragma unroll
      for (int i = 0; i < 4; i++) av[i] = *(const bf16x8*)&Ash[(wm * 64 + i * 16 + l16) * 64 + kk * 32 + quad * 8];
#pragma unroll
      for (int j = 0; j < 4; j++) bv[j] = *(const bf16x8*)&Bsh[(wn * 64 + j * 16 + l16) * 64 + kk * 32 + quad * 8];
#pragma unroll
      for (int i = 0; i < 4; i++)
#pragma unroll
        for (int j = 0; j < 4; j++)
          acc[i][j] = __builtin_amdgcn_mfma_f32_16x16x32_bf16(av[i], bv[j], acc[i][j], 0, 0, 0);
    }
  }

  const float* bias = ball + which * 256;
  const float scale = (which == 0) ? 0.25503486f : 1.0f;  // (1/sqrt(32))*log2(e) folded into Q
#pragma unroll
  for (int i = 0; i < 4; i++) {
#pragma unroll
    for (int j = 0; j < 4; j++) {
      const int mb = m0 + wm * 64 + i * 16 + quad * 4;
      const int n = n0 + wn * 64 + j * 16 + l16;
#pragma unroll
      for (int r = 0; r < 4; r++) {
        const int m = mb + r;
        float v = acc[i][j][r];
        if (which < 2) {
          v = (v + bias[n]) * scale;
          u16* D = (which ? Kb : Qb) + (size_t)b * 262144;
          D[(size_t)m * 256 + n] = f2bf(v);
        } else {
          v = v + bias[m];
          (Vb + (size_t)b * 262144)[(size_t)m * 1024 + n] = f2bf(v);
        }
      }
    }
  }
}

// ---------- fused attention v6: 32 q-rows/wave, 128-t K-tiles (16.9 KB LDS -> 6 blocks/CU) ----------
// S^T = mfma32(K-frag, Q-frag): lane holds P[q=l16][t=quad*4+r] per 16x16 tile --
// exactly the B-frag of mfma_f32_16x16x16bf16_1k. No LDS round-trip for P.
// exp2 builtin; (1/sqrt(32))*log2(e) folded into Q. grid 2048 linear:
// blk = qc*256 + bh -> XCD = bh%8 (all 8 q-chunks of a (b,h) share an XCD).
__global__ void __launch_bounds__(256) attn_kernel(const u16* __restrict__ Q,
                                                   const u16* __restrict__ K,
                                                   const u16* __restrict__ V,
                                                   u16* __restrict__ O) {
  const int blk = blockIdx.x;
  const int qc = blk >> 8, bh = blk & 255;
  const int b = bh >> 3, h = bh & 7;
  const int tid = threadIdx.x, wave = tid >> 6, lane = tid & 63;
  const int quad = lane >> 4, l16 = lane & 15;
  __shared__ u16 Ksh[128 * 32];   // (t, d) 64B rows, unpadded (gld16 dest)
  __shared__ u16 Vsh[32 * 136];   // (d, t) pitch 136 u16 = 272B -> ~2-way max
  const u16* Qg = Q + (size_t)b * 262144 + h * 32;
  const u16* Kg = K + (size_t)b * 262144 + h * 32;
  const u16* Vg = V + (size_t)b * 262144 + (size_t)h * 32768;
  const int qw = qc * 128 + wave * 32;   // this wave's 32 q rows

  bf16x8 qf[2];
#pragma unroll
  for (int qt = 0; qt < 2; qt++)
    qf[qt] = *(const bf16x8*)(Qg + (size_t)(qw + qt * 16 + l16) * 256 + quad * 8);

  f32x4 oacc[2][2];  // [dt][qt]: C[m=d][n=q]
#pragma unroll
  for (int dt = 0; dt < 2; dt++)
#pragma unroll
    for (int qt = 0; qt < 2; qt++) oacc[dt][qt] = (f32x4){0.f, 0.f, 0.f, 0.f};
  float lsum[2] = {0.f, 0.f};

  const int krow = lane >> 2, kcol = (lane & 3) * 8;   // K staging: 4 lanes/row
  for (int kt0 = 0; kt0 < 1024; kt0 += 128) {
    __syncthreads();   // WAR: prior tile's frag reads done
#pragma unroll
    for (int i = 0; i < 2; i++) {
      const int rb = wave * 32 + i * 16;
      gld16(Kg + (size_t)(kt0 + rb + krow) * 256 + kcol, &Ksh[rb * 32 + lane * 8]);
    }
    for (int c = tid; c < 512; c += 256) {
      const int r = c >> 4, off = (c & 15) * 8;
      *(uint4*)&Vsh[r * 136 + off] = *(const uint4*)(Vg + (size_t)r * 1024 + kt0 + off);
    }
    __syncthreads();   // drains vmcnt (gld16) + lgkm before barrier
#pragma unroll
    for (int sub = 0; sub < 4; sub++) {
      const int sk0 = sub * 32;
      bf16x4 pf[2][2];
#pragma unroll
      for (int mt = 0; mt < 2; mt++) {
        const bf16x8 kf = *(const bf16x8*)&Ksh[(sk0 + mt * 16 + l16) * 32 + quad * 8];
        f32x4 sf[2];
#pragma unroll
        for (int qt = 0; qt < 2; qt++)
          sf[qt] = __builtin_amdgcn_mfma_f32_16x16x32_bf16(
              kf, qf[qt], (f32x4){0.f, 0.f, 0.f, 0.f}, 0, 0, 0);
#pragma unroll
        for (int qt = 0; qt < 2; qt++) {
          const float p0 = __builtin_amdgcn_exp2f(sf[qt][0]);
          const float p1 = __builtin_amdgcn_exp2f(sf[qt][1]);
          const float p2 = __builtin_amdgcn_exp2f(sf[qt][2]);
          const float p3 = __builtin_amdgcn_exp2f(sf[qt][3]);
          lsum[qt] += (p0 + p1) + (p2 + p3);
          union { u32 u[2]; bf16x4 v; } pv;
          pv.u[0] = __builtin_amdgcn_perm(fbits(p1), fbits(p0), 0x07060302u);
          pv.u[1] = __builtin_amdgcn_perm(fbits(p3), fbits(p2), 0x07060302u);
          pf[mt][qt] = pv.v;
        }
      }
      bf16x4 vf[2][2];
#pragma unroll
      for (int dt = 0; dt < 2; dt++)
#pragma unroll
        for (int mt = 0; mt < 2; mt++)
          vf[dt][mt] = *(const bf16x4*)&Vsh[(dt * 16 + l16) * 136 + sk0 + mt * 16 + quad * 4];
#pragma unroll
      for (int mt = 0; mt < 2; mt++)
#pragma unroll
        for (int dt = 0; dt < 2; dt++)
#pragma unroll
          for (int qt = 0; qt < 2; qt++)
            oacc[dt][qt] = __builtin_amdgcn_mfma_f32_16x16x16bf16_1k(
                vf[dt][mt], pf[mt][qt], oacc[dt][qt], 0, 0, 0);
    }
  }

  float linv[2];
#pragma unroll
  for (int qt = 0; qt < 2; qt++) {
    float l = lsum[qt];
    l += __shfl_xor(l, 16);
    l += __shfl_xor(l, 32);
    linv[qt] = 1.0f / l;
  }
#pragma unroll
  for (int dt = 0; dt < 2; dt++)
#pragma unroll
    for (int qt = 0; qt < 2; qt++) {
      ushort4 st;
      st.x = f2bf(oacc[dt][qt][0] * linv[qt]);
      st.y = f2bf(oacc[dt][qt][1] * linv[qt]);
      st.z = f2bf(oacc[dt][qt][2] * linv[qt]);
      st.w = f2bf(oacc[dt][qt][3] * linv[qt]);
      *(ushort4*)(O + (size_t)(b * 1024 + qw + qt * 16 + l16) * 256 + h * 32 + dt * 16 + quad * 4) = st;
    }
}

// ---------- out projection + residual, BK=64: out = 2x + g*(Wo.O + bo) ----------
__global__ void __launch_bounds__(256) out_gemm(const u16* __restrict__ WoB,
                                                const float* __restrict__ bg,
                                                const u16* __restrict__ Ob,
                                                const void* __restrict__ xin,
                                                void* __restrict__ outp,
                                                const u32* __restrict__ xdet) {
  const int b = blockIdx.z;
  const int m0 = blockIdx.y * 128, n0 = blockIdx.x * 128;
  const int tid = threadIdx.x, lane = tid & 63, wave = tid >> 6;
  const int quad = lane >> 4, l16 = lane & 15;
  const int wm = wave >> 1, wn = wave & 1;
  const int isbf = detect_bf16(xdet);
  const u16* Bb = Ob + (size_t)b * 262144;
  __shared__ u16 Ash[8192], Bsh[8192];
  f32x4 acc[4][4];
#pragma unroll
  for (int i = 0; i < 4; i++)
#pragma unroll
    for (int j = 0; j < 4; j++) acc[i][j] = (f32x4){0.f, 0.f, 0.f, 0.f};

  const int srow = lane >> 3, scol = (lane & 7) * 8;
  for (int k0 = 0; k0 < 256; k0 += 64) {
    __syncthreads();
#pragma unroll
    for (int p = 0; p < 4; p++) {
      const int row = p * 32 + wave * 8;
      gld16(WoB + (size_t)(m0 + row + srow) * 256 + k0 + scol, &Ash[row * 64 + lane * 8]);
      gld16(Bb  + (size_t)(n0 + row + srow) * 256 + k0 + scol, &Bsh[row * 64 + lane * 8]);
    }
    __syncthreads();
#pragma unroll
    for (int kk = 0; kk < 2; kk++) {
      bf16x8 av[4], bv[4];
#pragma unroll
      for (int i = 0; i < 4; i++) av[i] = *(const bf16x8*)&Ash[(wm * 64 + i * 16 + l16) * 64 + kk * 32 + quad * 8];
#pragma unroll
      for (int j = 0; j < 4; j++) bv[j] = *(const bf16x8*)&Bsh[(wn * 64 + j * 16 + l16) * 64 + kk * 32 + quad * 8];
#pragma unroll
      for (int i = 0; i < 4; i++)
#pragma unroll
        for (int j = 0; j < 4; j++)
          acc[i][j] = __builtin_amdgcn_mfma_f32_16x16x32_bf16(av[i], bv[j], acc[i][j], 0, 0, 0);
    }
  }

  const float g = bg[256];
#pragma unroll
  for (int i = 0; i < 4; i++) {
#pragma unroll
    for (int j = 0; j < 4; j++) {
      const int mb = m0 + wm * 64 + i * 16 + quad * 4;
      const int n = n0 + wn * 64 + j * 16 + l16;
#pragma unroll
      for (int r = 0; r < 4; r++) {
        const int m = mb + r;
        const float v = acc[i][j][r] + bg[m];
        const size_t gi = (size_t)b * 262144 + (size_t)m * 1024 + n;
        const float xv = isbf ? bf2f(((const u16*)xin)[gi]) : ((const float*)xin)[gi];
        const float res = 2.f * xv + g * v;
        if (isbf) ((u16*)outp)[gi] = f2bf(res);
        else      ((float*)outp)[gi] = res;
      }
    }
  }
}

// ---------- launcher ----------
extern "C" void kernel_launch(void* const* d_in, const int* in_sizes, int n_in,
                              void* d_out, int out_size, void* d_ws, size_t ws_size,
                              hipStream_t stream) {
  const void* x  = d_in[0];
  const void* Wq = d_in[1]; const void* bq = d_in[2];
  const void* Wk = d_in[3]; const void* bk = d_in[4];
  const void* Wv = d_in[5]; const void* bv = d_in[6];
  const void* Wo = d_in[7]; const void* bo = d_in[8];
  const void* gm = d_in[9];

  u16* ws = (u16*)d_ws;
  u16* xT = ws;            // (b,s,c) bf16; reused as O after V-proj
  u16* Qb = ws + NT;       // (b,s,256), scale*log2e folded
  u16* Kb = ws + 2 * NT;   // (b,s,256)
  u16* Vb = ws + 3 * NT;   // (b,256,s)
  u16* Ob = xT;
  const u32* xdet = (const u32*)x;

  // d_out doubles as QKV-weight scratch until out_gemm rewrites it fully
  u16* WqkvB = (u16*)d_out;                              // 3 x 65536 u16
  float* bqkvF = (float*)((u16*)d_out + 196608);         // 768 f32

  // Wo scratch: ws tail if it fits (prep folded into prologue), else dead-Q fallback
  const bool tail = ws_size >= (size_t)(4 * NT + 66048) * 2;
  u16* WoB = tail ? (ws + 4 * NT) : Qb;
  float* boF = tail ? (float*)(ws + 4 * NT + 65536) : (float*)(Qb + 65536);

  prologue_kernel<<<dim3(tail ? 2304 : 2240), 256, 0, stream>>>(
      x, xT, Wq, Wk, Wv, bq, bk, bv, WqkvB, bqkvF, Wo, bo, gm, WoB, boF);
  qkv_gemm<<<dim3(2, 8, 96), 256, 0, stream>>>(xT, WqkvB, bqkvF, Qb, Kb, Vb);
  attn_kernel<<<dim3(2048), 256, 0, stream>>>(Qb, Kb, Vb, Ob);
  if (!tail) prep_o<<<dim3(64), 256, 0, stream>>>(Wo, bo, gm, WoB, boF, xdet);
  out_gemm<<<dim3(8, 2, 32), 256, 0, stream>>>(WoB, boF, Ob, x, d_out, xdet);
}

// Round 7
// 221.565 us; speedup vs baseline: 1.2375x; 1.0065x over previous
//
#include <hip/hip_runtime.h>
#include <stdint.h>

typedef unsigned short u16;
typedef unsigned int   u32;
typedef __attribute__((ext_vector_type(8))) short bf16x8;  // 8 bf16 = 4 VGPR
typedef __attribute__((ext_vector_type(4))) short bf16x4;  // 4 bf16 = 2 VGPR
typedef __attribute__((ext_vector_type(4))) float f32x4;   // MFMA C/D frag

#define NT ((size_t)8388608)   // 32*1024*256 elements

// ---------- helpers ----------
__device__ __forceinline__ float bf2f(u16 u) {
  union { float f; u32 i; } v; v.i = ((u32)u) << 16; return v.f;
}
__device__ __forceinline__ u16 f2bf(float f) {
  union { float f; u32 i; } v; v.f = f;
  u32 r = (v.i + 0x7fffu + ((v.i >> 16) & 1u)) >> 16;   // RNE
  return (u16)r;
}
__device__ __forceinline__ u32 fbits(float f) {
  union { float f; u32 i; } v; v.f = f; return v.i;
}
// bf16-vs-f32 buffer sniff (64-lane ballot on exponent-byte position)
__device__ __forceinline__ int detect_bf16(const u32* __restrict__ xd) {
  u32 w = xd[threadIdx.x & 63];
  u32 e = (w >> 8) & 0x7fu;
  unsigned long long m = __ballot((e >= 0x38u) && (e <= 0x41u));
  return __popcll(m) > 32;
}
// async 16B/lane global->LDS (dest = wave-uniform base + lane*16)
__device__ __forceinline__ void gld16(const void* g, void* l) {
  __builtin_amdgcn_global_load_lds((const __attribute__((address_space(1))) u32*)g,
                                   (__attribute__((address_space(3))) u32*)l, 16, 0, 0);
}

// ---------- prologue: x transpose (0..2047) + Wq/Wk/Wv prep (2048..2239) + optional Wo (2240..2303) ----------
__global__ void __launch_bounds__(256) prologue_kernel(const void* __restrict__ xin,
                                                       u16* __restrict__ xT,
                                                       const void* __restrict__ W0, const void* __restrict__ W1,
                                                       const void* __restrict__ W2, const void* __restrict__ b0,
                                                       const void* __restrict__ b1, const void* __restrict__ b2,
                                                       u16* __restrict__ wdst, float* __restrict__ bdst,
                                                       const void* __restrict__ Wo, const void* __restrict__ bo,
                                                       const void* __restrict__ gm, u16* __restrict__ wodst,
                                                       float* __restrict__ bodst) {
  const int blk = blockIdx.x;
  const int tid = threadIdx.x;
  const int isbf = detect_bf16((const u32*)xin);
  if (blk < 2048) {
    const int s0 = (blk & 15) * 64, c0 = ((blk >> 4) & 3) * 64, b = blk >> 6;
    __shared__ u16 T[64][72];  // [c-local][s-local], +8 pad
    if (isbf) {
      const u16* xp = (const u16*)xin;
      for (int t = tid; t < 512; t += 256) {
        int r = t >> 3, off = (t & 7) * 8;
        *(uint4*)&T[r][off] = *(const uint4*)(xp + ((size_t)(b * 256 + c0 + r)) * 1024 + s0 + off);
      }
    } else {
      const float* xp = (const float*)xin;
      for (int t = tid; t < 512; t += 256) {
        int r = t >> 3, off = (t & 7) * 8;
        const float* s = xp + ((size_t)(b * 256 + c0 + r)) * 1024 + s0 + off;
#pragma unroll
        for (int u = 0; u < 8; u++) T[r][off + u] = f2bf(s[u]);
      }
    }
    __syncthreads();
    for (int t = tid; t < 512; t += 256) {
      int r = t >> 3, off = (t & 7) * 8;   // r = s-local, off = c-local
      union { u16 h[8]; uint4 v; } pk;
#pragma unroll
      for (int u = 0; u < 8; u++) pk.h[u] = T[off + u][r];
      *(uint4*)(xT + ((size_t)(b * 1024 + s0 + r)) * 256 + c0 + off) = pk.v;
    }
  } else if (blk < 2240) {
    const int g = blk - 2048;            // 192 blocks: 64 per weight
    const int which = g >> 6, bk = g & 63;
    const void* Ws = which == 0 ? W0 : which == 1 ? W1 : W2;
    const void* bs = which == 0 ? b0 : which == 1 ? b1 : b2;
    const int idx = bk * 1024 + tid * 4;
    u16* dst = wdst + which * 65536 + idx;
    if (isbf) {
      *(ushort4*)dst = *(const ushort4*)((const u16*)Ws + idx);
    } else {
      const float* s = (const float*)Ws + idx;
      ushort4 o; o.x = f2bf(s[0]); o.y = f2bf(s[1]); o.z = f2bf(s[2]); o.w = f2bf(s[3]);
      *(ushort4*)dst = o;
    }
    if (bk == 0) {
      bdst[which * 256 + tid] = isbf ? bf2f(((const u16*)bs)[tid]) : ((const float*)bs)[tid];
    }
  } else {
    const int g = blk - 2240;            // 64 blocks: Wo
    const int idx = g * 1024 + tid * 4;
    if (isbf) {
      *(ushort4*)(wodst + idx) = *(const ushort4*)((const u16*)Wo + idx);
    } else {
      const float* s = (const float*)Wo + idx;
      ushort4 o; o.x = f2bf(s[0]); o.y = f2bf(s[1]); o.z = f2bf(s[2]); o.w = f2bf(s[3]);
      *(ushort4*)(wodst + idx) = o;
    }
    if (g == 0) {
      bodst[tid] = isbf ? bf2f(((const u16*)bo)[tid]) : ((const float*)bo)[tid];
      if (tid == 0) bodst[256] = isbf ? bf2f(((const u16*)gm)[0]) : ((const float*)gm)[0];
    }
  }
}

// ---------- Wo prep fallback (when ws tail unavailable; runs after attn) ----------
__global__ void __launch_bounds__(256) prep_o(const void* __restrict__ Wo, const void* __restrict__ bo,
                                              const void* __restrict__ gm, u16* __restrict__ wdst,
                                              float* __restrict__ bdst, const u32* __restrict__ xdet) {
  const int isbf = detect_bf16(xdet);
  const int idx = blockIdx.x * 1024 + threadIdx.x * 4;
  if (isbf) {
    *(ushort4*)(wdst + idx) = *(const ushort4*)((const u16*)Wo + idx);
  } else {
    const float* s = (const float*)Wo + idx;
    ushort4 o; o.x = f2bf(s[0]); o.y = f2bf(s[1]); o.z = f2bf(s[2]); o.w = f2bf(s[3]);
    *(ushort4*)(wdst + idx) = o;
  }
  if (blockIdx.x == 0) {
    int t = threadIdx.x;
    bdst[t] = isbf ? bf2f(((const u16*)bo)[t]) : ((const float*)bo)[t];
    if (t == 0) bdst[256] = isbf ? bf2f(((const u16*)gm)[0]) : ((const float*)gm)[0];
  }
}

// ---------- fused QKV projection, BK=64: one launch, z = b*3 + which ----------
__global__ void __launch_bounds__(256) qkv_gemm(const u16* __restrict__ xT,
                                                const u16* __restrict__ Wall,
                                                const float* __restrict__ ball,
                                                u16* __restrict__ Qb, u16* __restrict__ Kb,
                                                u16* __restrict__ Vb) {
  const int z = blockIdx.z, b = z / 3, which = z - b * 3;
  const int tid = threadIdx.x, lane = tid & 63, wave = tid >> 6;
  const int quad = lane >> 4, l16 = lane & 15;
  const int wm = wave >> 1, wn = wave & 1;
  const u16* xb = xT + (size_t)b * 262144;
  const u16* W = Wall + which * 65536;
  int m0, n0; const u16 *Abase, *Bbase;
  if (which < 2) { m0 = blockIdx.y * 128; n0 = blockIdx.x * 128; Abase = xb; Bbase = W; }
  else           { m0 = blockIdx.x * 128; n0 = blockIdx.y * 128; Abase = W; Bbase = xb; }

  __shared__ u16 Ash[8192], Bsh[8192];   // 128 rows x 64 (128B rows)
  f32x4 acc[4][4];
#pragma unroll
  for (int i = 0; i < 4; i++)
#pragma unroll
    for (int j = 0; j < 4; j++) acc[i][j] = (f32x4){0.f, 0.f, 0.f, 0.f};

  const int srow = lane >> 3, scol = (lane & 7) * 8;
  for (int k0 = 0; k0 < 256; k0 += 64) {
    __syncthreads();   // WAR: prior frag reads done before restage lands
#pragma unroll
    for (int p = 0; p < 4; p++) {
      const int row = p * 32 + wave * 8;
      gld16(Abase + (size_t)(m0 + row + srow) * 256 + k0 + scol, &Ash[row * 64 + lane * 8]);
      gld16(Bbase + (size_t)(n0 + row + srow) * 256 + k0 + scol, &Bsh[row * 64 + lane * 8]);
    }
    __syncthreads();   // drains vmcnt before barrier
#pragma unroll
    for (int kk = 0; kk < 2; kk++) {
      bf16x8 av[4], bv[4];
#pragma unroll
      for (int i = 0; i < 4; i++) av[i] = *(const bf16x8*)&Ash[(wm * 64 + i * 16 + l16) * 64 + kk * 32 + quad * 8];
#pragma unroll
      for (int j = 0; j < 4; j++) bv[j] = *(const bf16x8*)&Bsh[(wn * 64 + j * 16 + l16) * 64 + kk * 32 + quad * 8];
#pragma unroll
      for (int i = 0; i < 4; i++)
#pragma unroll
        for (int j = 0; j < 4; j++)
          acc[i][j] = __builtin_amdgcn_mfma_f32_16x16x32_bf16(av[i], bv[j], acc[i][j], 0, 0, 0);
    }
  }

  const float* bias = ball + which * 256;
  const float scale = (which == 0) ? 0.25503486f : 1.0f;  // (1/sqrt(32))*log2(e) folded into Q
#pragma unroll
  for (int i = 0; i < 4; i++) {
#pragma unroll
    for (int j = 0; j < 4; j++) {
      const int mb = m0 + wm * 64 + i * 16 + quad * 4;
      const int n = n0 + wn * 64 + j * 16 + l16;
#pragma unroll
      for (int r = 0; r < 4; r++) {
        const int m = mb + r;
        float v = acc[i][j][r];
        if (which < 2) {
          v = (v + bias[n]) * scale;
          u16* D = (which ? Kb : Qb) + (size_t)b * 262144;
          D[(size_t)m * 256 + n] = f2bf(v);
        } else {
          v = v + bias[m];
          (Vb + (size_t)b * 262144)[(size_t)m * 1024 + n] = f2bf(v);
        }
      }
    }
  }
}

// ---------- fused attention v7: 512 threads (8 waves x 32 q-rows = 256 q/block) ----------
// Halves K/V L2 re-fetch vs v6 (4 blocks per (b,h) instead of 8) and hits the
// 32-wave/CU HW occupancy cap (grid 1024 = 4 blocks/CU x 8 waves, VGPR<=64).
// S^T = mfma32(K-frag, Q-frag): lane holds P[q=l16][t=quad*4+r] per 16x16 tile --
// exactly the B-frag of mfma_f32_16x16x16bf16_1k. No LDS round-trip for P.
// exp2 builtin; (1/sqrt(32))*log2(e) folded into Q. grid 1024 linear:
// blk = qc*256 + bh -> XCD = bh%8 (all 4 q-chunks of a (b,h) share an XCD).
__global__ void __launch_bounds__(512) attn_kernel(const u16* __restrict__ Q,
                                                   const u16* __restrict__ K,
                                                   const u16* __restrict__ V,
                                                   u16* __restrict__ O) {
  const int blk = blockIdx.x;
  const int qc = blk >> 8, bh = blk & 255;
  const int b = bh >> 3, h = bh & 7;
  const int tid = threadIdx.x, wave = tid >> 6, lane = tid & 63;
  const int quad = lane >> 4, l16 = lane & 15;
  __shared__ u16 Ksh[128 * 32];   // (t, d) 64B rows, unpadded (gld16 dest)
  __shared__ u16 Vsh[32 * 136];   // (d, t) pitch 136 u16 = 272B -> ~2-way max
  const u16* Qg = Q + (size_t)b * 262144 + h * 32;
  const u16* Kg = K + (size_t)b * 262144 + h * 32;
  const u16* Vg = V + (size_t)b * 262144 + (size_t)h * 32768;
  const int qw = qc * 256 + wave * 32;   // this wave's 32 q rows

  bf16x8 qf[2];
#pragma unroll
  for (int qt = 0; qt < 2; qt++)
    qf[qt] = *(const bf16x8*)(Qg + (size_t)(qw + qt * 16 + l16) * 256 + quad * 8);

  f32x4 oacc[2][2];  // [dt][qt]: C[m=d][n=q]
#pragma unroll
  for (int dt = 0; dt < 2; dt++)
#pragma unroll
    for (int qt = 0; qt < 2; qt++) oacc[dt][qt] = (f32x4){0.f, 0.f, 0.f, 0.f};
  float lsum[2] = {0.f, 0.f};

  const int krow = lane >> 2, kcol = (lane & 3) * 8;   // K staging: 4 lanes/row
  for (int kt0 = 0; kt0 < 1024; kt0 += 128) {
    __syncthreads();   // WAR: prior tile's frag reads done
    {   // K tile: 128 rows x 64B; wave w stages rows w*16..w*16+15 (one gld16)
      const int rb = wave * 16;
      gld16(Kg + (size_t)(kt0 + rb + krow) * 256 + kcol, &Ksh[rb * 32 + lane * 8]);
    }
    for (int c = tid; c < 1024; c += 512) {
      const int r = c >> 5, off = (c & 31) * 8;
      if (r < 32) *(uint4*)&Vsh[r * 136 + off] = *(const uint4*)(Vg + (size_t)r * 1024 + kt0 + off);
    }
    __syncthreads();   // drains vmcnt (gld16) + lgkm before barrier
#pragma unroll
    for (int sub = 0; sub < 4; sub++) {
      const int sk0 = sub * 32;
      bf16x4 pf[2][2];
#pragma unroll
      for (int mt = 0; mt < 2; mt++) {
        const bf16x8 kf = *(const bf16x8*)&Ksh[(sk0 + mt * 16 + l16) * 32 + quad * 8];
        f32x4 sf[2];
#pragma unroll
        for (int qt = 0; qt < 2; qt++)
          sf[qt] = __builtin_amdgcn_mfma_f32_16x16x32_bf16(
              kf, qf[qt], (f32x4){0.f, 0.f, 0.f, 0.f}, 0, 0, 0);
#pragma unroll
        for (int qt = 0; qt < 2; qt++) {
          const float p0 = __builtin_amdgcn_exp2f(sf[qt][0]);
          const float p1 = __builtin_amdgcn_exp2f(sf[qt][1]);
          const float p2 = __builtin_amdgcn_exp2f(sf[qt][2]);
          const float p3 = __builtin_amdgcn_exp2f(sf[qt][3]);
          lsum[qt] += (p0 + p1) + (p2 + p3);
          union { u32 u[2]; bf16x4 v; } pv;
          pv.u[0] = __builtin_amdgcn_perm(fbits(p1), fbits(p0), 0x07060302u);
          pv.u[1] = __builtin_amdgcn_perm(fbits(p3), fbits(p2), 0x07060302u);
          pf[mt][qt] = pv.v;
        }
      }
      bf16x4 vf[2][2];
#pragma unroll
      for (int dt = 0; dt < 2; dt++)
#pragma unroll
        for (int mt = 0; mt < 2; mt++)
          vf[dt][mt] = *(const bf16x4*)&Vsh[(dt * 16 + l16) * 136 + sk0 + mt * 16 + quad * 4];
#pragma unroll
      for (int mt = 0; mt < 2; mt++)
#pragma unroll
        for (int dt = 0; dt < 2; dt++)
#pragma unroll
          for (int qt = 0; qt < 2; qt++)
            oacc[dt][qt] = __builtin_amdgcn_mfma_f32_16x16x16bf16_1k(
                vf[dt][mt], pf[mt][qt], oacc[dt][qt], 0, 0, 0);
    }
  }

  float linv[2];
#pragma unroll
  for (int qt = 0; qt < 2; qt++) {
    float l = lsum[qt];
    l += __shfl_xor(l, 16);
    l += __shfl_xor(l, 32);
    linv[qt] = 1.0f / l;
  }
#pragma unroll
  for (int dt = 0; dt < 2; dt++)
#pragma unroll
    for (int qt = 0; qt < 2; qt++) {
      ushort4 st;
      st.x = f2bf(oacc[dt][qt][0] * linv[qt]);
      st.y = f2bf(oacc[dt][qt][1] * linv[qt]);
      st.z = f2bf(oacc[dt][qt][2] * linv[qt]);
      st.w = f2bf(oacc[dt][qt][3] * linv[qt]);
      *(ushort4*)(O + (size_t)(b * 1024 + qw + qt * 16 + l16) * 256 + h * 32 + dt * 16 + quad * 4) = st;
    }
}

// ---------- out projection + residual, BK=64: out = 2x + g*(Wo.O + bo) ----------
__global__ void __launch_bounds__(256) out_gemm(const u16* __restrict__ WoB,
                                                const float* __restrict__ bg,
                                                const u16* __restrict__ Ob,
                                                const void* __restrict__ xin,
                                                void* __restrict__ outp,
                                                const u32* __restrict__ xdet) {
  const int b = blockIdx.z;
  const int m0 = blockIdx.y * 128, n0 = blockIdx.x * 128;
  const int tid = threadIdx.x, lane = tid & 63, wave = tid >> 6;
  const int quad = lane >> 4, l16 = lane & 15;
  const int wm = wave >> 1, wn = wave & 1;
  const int isbf = detect_bf16(xdet);
  const u16* Bb = Ob + (size_t)b * 262144;
  __shared__ u16 Ash[8192], Bsh[8192];
  f32x4 acc[4][4];
#pragma unroll
  for (int i = 0; i < 4; i++)
#pragma unroll
    for (int j = 0; j < 4; j++) acc[i][j] = (f32x4){0.f, 0.f, 0.f, 0.f};

  const int srow = lane >> 3, scol = (lane & 7) * 8;
  for (int k0 = 0; k0 < 256; k0 += 64) {
    __syncthreads();
#pragma unroll
    for (int p = 0; p < 4; p++) {
      const int row = p * 32 + wave * 8;
      gld16(WoB + (size_t)(m0 + row + srow) * 256 + k0 + scol, &Ash[row * 64 + lane * 8]);
      gld16(Bb  + (size_t)(n0 + row + srow) * 256 + k0 + scol, &Bsh[row * 64 + lane * 8]);
    }
    __syncthreads();
#pragma unroll
    for (int kk = 0; kk < 2; kk++) {
      bf16x8 av[4], bv[4];
#pragma unroll
      for (int i = 0; i < 4; i++) av[i] = *(const bf16x8*)&Ash[(wm * 64 + i * 16 + l16) * 64 + kk * 32 + quad * 8];
#pragma unroll
      for (int j = 0; j < 4; j++) bv[j] = *(const bf16x8*)&Bsh[(wn * 64 + j * 16 + l16) * 64 + kk * 32 + quad * 8];
#pragma unroll
      for (int i = 0; i < 4; i++)
#pragma unroll
        for (int j = 0; j < 4; j++)
          acc[i][j] = __builtin_amdgcn_mfma_f32_16x16x32_bf16(av[i], bv[j], acc[i][j], 0, 0, 0);
    }
  }

  const float g = bg[256];
#pragma unroll
  for (int i = 0; i < 4; i++) {
#pragma unroll
    for (int j = 0; j < 4; j++) {
      const int mb = m0 + wm * 64 + i * 16 + quad * 4;
      const int n = n0 + wn * 64 + j * 16 + l16;
#pragma unroll
      for (int r = 0; r < 4; r++) {
        const int m = mb + r;
        const float v = acc[i][j][r] + bg[m];
        const size_t gi = (size_t)b * 262144 + (size_t)m * 1024 + n;
        const float xv = isbf ? bf2f(((const u16*)xin)[gi]) : ((const float*)xin)[gi];
        const float res = 2.f * xv + g * v;
        if (isbf) ((u16*)outp)[gi] = f2bf(res);
        else      ((float*)outp)[gi] = res;
      }
    }
  }
}

// ---------- launcher ----------
extern "C" void kernel_launch(void* const* d_in, const int* in_sizes, int n_in,
                              void* d_out, int out_size, void* d_ws, size_t ws_size,
                              hipStream_t stream) {
  const void* x  = d_in[0];
  const void* Wq = d_in[1]; const void* bq = d_in[2];
  const void* Wk = d_in[3]; const void* bk = d_in[4];
  const void* Wv = d_in[5]; const void* bv = d_in[6];
  const void* Wo = d_in[7]; const void* bo = d_in[8];
  const void* gm = d_in[9];

  u16* ws = (u16*)d_ws;
  u16* xT = ws;            // (b,s,c) bf16; reused as O after V-proj
  u16* Qb = ws + NT;       // (b,s,256), scale*log2e folded
  u16* Kb = ws + 2 * NT;   // (b,s,256)
  u16* Vb = ws + 3 * NT;   // (b,256,s)
  u16* Ob = xT;
  const u32* xdet = (const u32*)x;

  // d_out doubles as QKV-weight scratch until out_gemm rewrites it fully
  u16* WqkvB = (u16*)d_out;                              // 3 x 65536 u16
  float* bqkvF = (float*)((u16*)d_out + 196608);         // 768 f32

  // Wo scratch: ws tail if it fits (prep folded into prologue), else dead-Q fallback
  const bool tail = ws_size >= (size_t)(4 * NT + 66048) * 2;
  u16* WoB = tail ? (ws + 4 * NT) : Qb;
  float* boF = tail ? (float*)(ws + 4 * NT + 65536) : (float*)(Qb + 65536);

  prologue_kernel<<<dim3(tail ? 2304 : 2240), 256, 0, stream>>>(
      x, xT, Wq, Wk, Wv, bq, bk, bv, WqkvB, bqkvF, Wo, bo, gm, WoB, boF);
  qkv_gemm<<<dim3(2, 8, 96), 256, 0, stream>>>(xT, WqkvB, bqkvF, Qb, Kb, Vb);
  attn_kernel<<<dim3(1024), 512, 0, stream>>>(Qb, Kb, Vb, Ob);
  if (!tail) prep_o<<<dim3(64), 256, 0, stream>>>(Wo, bo, gm, WoB, boF, xdet);
  out_gemm<<<dim3(8, 2, 32), 256, 0, stream>>>(WoB, boF, Ob, x, d_out, xdet);
}